// Round 1
// baseline (485.830 us; speedup 1.0000x reference)
//
#include <hip/hip_runtime.h>
#include <math.h>

#define BB 32
#define NCLS 15
#define HH 256
#define WW 256
#define KK 500
#define HW (HH*WW)                 // 65536
#define NELEM (BB*NCLS*HW)         // 31457280
#define N4 (NELEM/4)               // 7864320
#define NM (BB*NCLS*16*16)         // 122880 multiplier slots
#define BK (BB*KK)                 // 16000

// ws layout (floats):
//  f[0] = S (accumulates sum of gamma_c * (pos+neg))
//  f[1] = num_pos
//  i[2] = last index (int, init -1)
//  f[4 .. 4+BK)        = l_bk flat
//  f[16384 .. 16384+NM) = multiplier table M (init 1.0)
#define OFF_LBK 4
#define OFF_M   16384

__constant__ float c_gammas[15] = {2.7f,2.1f,2.4f,2.0f,3.0f,2.9f,3.0f,2.5f,
                                   2.1f,2.6f,2.0f,2.1f,2.7f,2.4f,2.2f};

__device__ __forceinline__ float contrib(float p, float gam, float g) {
    float pos_ind = (g == 1.0f) ? 1.0f : 0.0f;
    float neg_ind = (g <  1.0f) ? 1.0f : 0.0f;
    float t  = 1.0f - g;
    float t2 = t * t;
    float negw = t2 * t2;                       // (1-gt)^4
    float pos = __logf(p + 1e-12f)        * __powf(1.0f - p, gam) * pos_ind;
    float neg = __logf(1.0f - p + 1e-12f) * __powf(p,        gam) * negw * neg_ind;
    return pos + neg;
}

__device__ __forceinline__ float blockReduceSum(float v) {
    __shared__ float sh[4];
    #pragma unroll
    for (int o = 32; o > 0; o >>= 1) v += __shfl_down(v, o);
    int lane = threadIdx.x & 63, w = threadIdx.x >> 6;
    if (lane == 0) sh[w] = v;
    __syncthreads();
    float r = 0.0f;
    if (threadIdx.x == 0) r = sh[0] + sh[1] + sh[2] + sh[3];
    __syncthreads();
    return r;   // valid on thread 0 only
}

// ---- init: zero scalars, last=-1, M=1.0 ----
__global__ __launch_bounds__(256) void k_init(float* ws) {
    int i = blockIdx.x * blockDim.x + threadIdx.x;
    if (i == 0) {
        ws[0] = 0.0f;
        ws[1] = 0.0f;
        ((int*)ws)[2] = -1;
    }
    if (i < NM) ws[OFF_M + i] = 1.0f;
}

// ---- per-(b,k): huber mean, l_bk, last, scatter-multiply into M ----
__global__ __launch_bounds__(256) void k_bk(const float* __restrict__ output,
                                            const int*   __restrict__ mask,
                                            const int*   __restrict__ ind,
                                            const float* __restrict__ target,
                                            const int*   __restrict__ inde,
                                            float* ws) {
    int t = blockIdx.x * blockDim.x + threadIdx.x;
    if (t >= BK) return;
    int b = t / KK;
    int pos = ind[t];                                    // 0..HW-1
    const float* ob = output + (size_t)b * 2 * HW;
    float p0 = ob[pos];
    float p1 = ob[HW + pos];
    float d0 = p0 - target[t*2 + 0];
    float d1 = p1 - target[t*2 + 1];
    float a0 = fabsf(d0), a1 = fabsf(d1);
    float h0 = (a0 < 1.0f) ? 0.5f*d0*d0 : a0 - 0.5f;
    float h1 = (a1 < 1.0f) ? 0.5f*d1*d1 : a1 - 0.5f;
    float l  = 0.5f * (h0 + h1);
    ws[OFF_LBK + t] = l;
    if (mask[t] != 0) {
        atomicMax(((int*)ws) + 2, t);
        float factor = atanf(l) * 0.63661977236758134308f;  // 2/pi
        int ch = inde[t*3 + 0];
        int yy = inde[t*3 + 1];
        int xx = inde[t*3 + 2];
        int mi = ((b*NCLS + ch)*16 + yy)*16 + xx;
        unsigned int* addr = (unsigned int*)(ws + OFF_M + mi);
        unsigned int old = *addr, assumed;
        do {
            assumed = old;
            float nv = __uint_as_float(assumed) * factor;
            old = atomicCAS(addr, assumed, __float_as_uint(nv));
        } while (old != assumed);
    }
}

// ---- main reduction over pred/gt with ORIGINAL pred ----
__global__ __launch_bounds__(256) void k_main(const float4* __restrict__ pred,
                                              const float4* __restrict__ gt,
                                              float* ws) {
    float acc = 0.0f, np = 0.0f;
    int stride = gridDim.x * blockDim.x;
    for (int i = blockIdx.x * blockDim.x + threadIdx.x; i < N4; i += stride) {
        float4 p = pred[i];
        float4 g = gt[i];
        float gam = c_gammas[(i >> 14) % 15];    // 4 consecutive elems share channel
        float e = contrib(p.x, gam, g.x) + contrib(p.y, gam, g.y)
                + contrib(p.z, gam, g.z) + contrib(p.w, gam, g.w);
        acc += gam * e;
        np  += ((g.x == 1.0f) ? 1.0f : 0.0f) + ((g.y == 1.0f) ? 1.0f : 0.0f)
             + ((g.z == 1.0f) ? 1.0f : 0.0f) + ((g.w == 1.0f) ? 1.0f : 0.0f);
    }
    float bs = blockReduceSum(acc);
    if (threadIdx.x == 0) atomicAdd(&ws[0], bs);
    float bn = blockReduceSum(np);
    if (threadIdx.x == 0 && bn != 0.0f) atomicAdd(&ws[1], bn);
}

// ---- correction at scatter-modified locations ----
__global__ __launch_bounds__(256) void k_corr(const float* __restrict__ pred,
                                              const float* __restrict__ gt,
                                              float* ws) {
    int i = blockIdx.x * blockDim.x + threadIdx.x;
    float acc = 0.0f;
    if (i < NM) {
        float m = ws[OFF_M + i];
        if (m != 1.0f) {
            int x  = i & 15;
            int y  = (i >> 4) & 15;
            int bc = i >> 8;
            int c  = bc % NCLS;
            size_t off = ((size_t)bc << 16) + (size_t)(y * WW + x);
            float p = pred[off];
            float g = gt[off];
            float gam = c_gammas[c];
            acc = gam * (contrib(p * m, gam, g) - contrib(p, gam, g));
        }
    }
    float bs = blockReduceSum(acc);
    if (threadIdx.x == 0 && bs != 0.0f) atomicAdd(&ws[0], bs);
}

// ---- finalize ----
__global__ void k_fin(const float* ws, float* out) {
    int last = ((const int*)ws)[2];
    float loss0 = (last >= 0) ? ws[OFF_LBK + last] : 0.0f;
    float loss = loss0 - 0.5f * ws[0];
    float np = ws[1];
    out[0] = (np == 0.0f) ? loss : loss / np;
}

extern "C" void kernel_launch(void* const* d_in, const int* in_sizes, int n_in,
                              void* d_out, int out_size, void* d_ws, size_t ws_size,
                              hipStream_t stream) {
    const float* pred   = (const float*)d_in[0];
    const float* gt     = (const float*)d_in[1];
    const float* output = (const float*)d_in[2];
    const int*   mask   = (const int*)d_in[3];
    const int*   ind    = (const int*)d_in[4];
    const float* target = (const float*)d_in[5];
    const int*   inde   = (const int*)d_in[6];
    float* ws  = (float*)d_ws;
    float* out = (float*)d_out;

    k_init<<<(NM + 255)/256, 256, 0, stream>>>(ws);
    k_bk  <<<(BK + 255)/256, 256, 0, stream>>>(output, mask, ind, target, inde, ws);
    k_main<<<4096, 256, 0, stream>>>((const float4*)pred, (const float4*)gt, ws);
    k_corr<<<(NM + 255)/256, 256, 0, stream>>>(pred, gt, ws);
    k_fin <<<1, 1, 0, stream>>>(ws, out);
}

// Round 3
// 301.217 us; speedup vs baseline: 1.6129x; 1.6129x over previous
//
#include <hip/hip_runtime.h>
#include <math.h>

#define BB 32
#define NCLS 15
#define HH 256
#define WW 256
#define KK 500
#define HW (HH*WW)                 // 65536
#define NELEM (BB*NCLS*HW)         // 31457280
#define N4 (NELEM/4)               // 7864320
#define NM (BB*NCLS*16*16)         // 122880 multiplier slots
#define BK (BB*KK)                 // 16000

// ws layout (floats):
//  f[0] = S (accumulates sum of gamma_c * (pos+neg))
//  f[1] = num_pos
//  i[2] = last index (int, init -1)
//  f[4 .. 4+BK)        = l_bk flat
//  f[16384 .. 16384+NM) = multiplier table M (init 1.0)
#define OFF_LBK 4
#define OFF_M   16384

__constant__ float c_gammas[15] = {2.7f,2.1f,2.4f,2.0f,3.0f,2.9f,3.0f,2.5f,
                                   2.1f,2.6f,2.0f,2.1f,2.7f,2.4f,2.2f};

// Raw HW transcendentals (avoid glibc name collisions with __exp2f/__log2f):
//   v_exp_f32: 2^x, v_log_f32: log2(x)
#define EXP2F(x) __builtin_amdgcn_exp2f(x)
#define LOG2F(x) __builtin_amdgcn_logf(x)
#define LN2 0.69314718055994530942f

// Per-element loss contribution (without the gamma_c outer weight).
// pos term only fires when g == 1.0 exactly — for uniform[0,1) gt this is
// never, so the branch is wave-uniformly skipped; still exact if taken.
// pow via native exp2/log2: __powf lowers to __ocml_pow_f32 (~200 instr)
// which was the R1 bottleneck (VALUBusy ~100%, 318 us).
__device__ __forceinline__ float elem(float p, float g, float gam, float& np) {
    float t    = 1.0f - g;
    float t2   = t * t;
    float negw = (g < 1.0f) ? t2 * t2 : 0.0f;          // (1-g)^4 * neg_ind
    float pw   = EXP2F(gam * LOG2F(p));                // p^gam (0 -> 0)
    float v    = (LN2 * LOG2F(1.0f - p + 1e-12f)) * pw * negw;
    if (g == 1.0f) {                                   // ~never taken
        np += 1.0f;
        v += (LN2 * LOG2F(p + 1e-12f)) * EXP2F(gam * LOG2F(1.0f - p));
    }
    return v;
}

__device__ __forceinline__ float blockReduceSum(float v) {
    __shared__ float sh[4];
    #pragma unroll
    for (int o = 32; o > 0; o >>= 1) v += __shfl_down(v, o);
    int lane = threadIdx.x & 63, w = threadIdx.x >> 6;
    if (lane == 0) sh[w] = v;
    __syncthreads();
    float r = 0.0f;
    if (threadIdx.x == 0) r = sh[0] + sh[1] + sh[2] + sh[3];
    __syncthreads();
    return r;   // valid on thread 0 only
}

// ---- init: zero scalars, last=-1, M=1.0 ----
__global__ __launch_bounds__(256) void k_init(float* ws) {
    int i = blockIdx.x * blockDim.x + threadIdx.x;
    if (i == 0) {
        ws[0] = 0.0f;
        ws[1] = 0.0f;
        ((int*)ws)[2] = -1;
    }
    if (i < NM) ws[OFF_M + i] = 1.0f;
}

// ---- per-(b,k): huber mean, l_bk, last, scatter-multiply into M ----
__global__ __launch_bounds__(256) void k_bk(const float* __restrict__ output,
                                            const int*   __restrict__ mask,
                                            const int*   __restrict__ ind,
                                            const float* __restrict__ target,
                                            const int*   __restrict__ inde,
                                            float* ws) {
    int t = blockIdx.x * blockDim.x + threadIdx.x;
    bool valid = (t < BK);
    int lastv = -1;
    if (valid) {
        int b = t / KK;
        int pos = ind[t];                                    // 0..HW-1
        const float* ob = output + (size_t)b * 2 * HW;
        float p0 = ob[pos];
        float p1 = ob[HW + pos];
        float d0 = p0 - target[t*2 + 0];
        float d1 = p1 - target[t*2 + 1];
        float a0 = fabsf(d0), a1 = fabsf(d1);
        float h0 = (a0 < 1.0f) ? 0.5f*d0*d0 : a0 - 0.5f;
        float h1 = (a1 < 1.0f) ? 0.5f*d1*d1 : a1 - 0.5f;
        float l  = 0.5f * (h0 + h1);
        ws[OFF_LBK + t] = l;
        if (mask[t] != 0) {
            lastv = t;
            float factor = atanf(l) * 0.63661977236758134308f;  // 2/pi
            int ch = inde[t*3 + 0];
            int yy = inde[t*3 + 1];
            int xx = inde[t*3 + 2];
            int mi = ((b*NCLS + ch)*16 + yy)*16 + xx;
            unsigned int* addr = (unsigned int*)(ws + OFF_M + mi);
            unsigned int old = *addr, assumed;
            do {
                assumed = old;
                float nv = __uint_as_float(assumed) * factor;
                old = atomicCAS(addr, assumed, __float_as_uint(nv));
            } while (old != assumed);
        }
    }
    // block-level max of lastv -> one atomicMax per block (G12)
    __shared__ int shm[4];
    int v = lastv;
    #pragma unroll
    for (int o = 32; o > 0; o >>= 1) v = max(v, __shfl_down(v, o));
    int lane = threadIdx.x & 63, w = threadIdx.x >> 6;
    if (lane == 0) shm[w] = v;
    __syncthreads();
    if (threadIdx.x == 0) {
        int m = max(max(shm[0], shm[1]), max(shm[2], shm[3]));
        if (m >= 0) atomicMax(((int*)ws) + 2, m);
    }
}

// ---- main reduction over pred/gt with ORIGINAL pred ----
// grid = (8, NCLS, B): gamma is wave-uniform, hoisted; 8x256 threads
// cover one 64K-element (b,c) plane in 8 float4-iterations each.
__global__ __launch_bounds__(256) void k_main(const float4* __restrict__ pred,
                                              const float4* __restrict__ gt,
                                              float* ws) {
    int c = blockIdx.y, b = blockIdx.z;
    float gam = c_gammas[c];
    size_t base = ((size_t)(b * NCLS + c)) << 14;   // float4 base (HW/4 = 16384)
    float acc = 0.0f, np = 0.0f;
    #pragma unroll 2
    for (int j = blockIdx.x * 256 + threadIdx.x; j < (HW/4); j += 8 * 256) {
        float4 p = pred[base + j];
        float4 g = gt[base + j];
        acc += elem(p.x, g.x, gam, np) + elem(p.y, g.y, gam, np)
             + elem(p.z, g.z, gam, np) + elem(p.w, g.w, gam, np);
    }
    acc *= gam;
    float bs = blockReduceSum(acc);
    if (threadIdx.x == 0 && bs != 0.0f) atomicAdd(&ws[0], bs);
    float bn = blockReduceSum(np);
    if (threadIdx.x == 0 && bn != 0.0f) atomicAdd(&ws[1], bn);
}

// ---- correction at scatter-modified locations ----
__global__ __launch_bounds__(256) void k_corr(const float* __restrict__ pred,
                                              const float* __restrict__ gt,
                                              float* ws) {
    int i = blockIdx.x * blockDim.x + threadIdx.x;
    float acc = 0.0f, dummy = 0.0f;
    if (i < NM) {
        float m = ws[OFF_M + i];
        if (m != 1.0f) {
            int x  = i & 15;
            int y  = (i >> 4) & 15;
            int bc = i >> 8;
            int c  = bc % NCLS;
            size_t off = ((size_t)bc << 16) + (size_t)(y * WW + x);
            float p = pred[off];
            float g = gt[off];
            float gam = c_gammas[c];
            acc = gam * (elem(p * m, g, gam, dummy) - elem(p, g, gam, dummy));
        }
    }
    float bs = blockReduceSum(acc);
    if (threadIdx.x == 0 && bs != 0.0f) atomicAdd(&ws[0], bs);
}

// ---- finalize ----
__global__ void k_fin(const float* ws, float* out) {
    int last = ((const int*)ws)[2];
    float loss0 = (last >= 0) ? ws[OFF_LBK + last] : 0.0f;
    float loss = loss0 - 0.5f * ws[0];
    float np = ws[1];
    out[0] = (np == 0.0f) ? loss : loss / np;
}

extern "C" void kernel_launch(void* const* d_in, const int* in_sizes, int n_in,
                              void* d_out, int out_size, void* d_ws, size_t ws_size,
                              hipStream_t stream) {
    const float* pred   = (const float*)d_in[0];
    const float* gt     = (const float*)d_in[1];
    const float* output = (const float*)d_in[2];
    const int*   mask   = (const int*)d_in[3];
    const int*   ind    = (const int*)d_in[4];
    const float* target = (const float*)d_in[5];
    const int*   inde   = (const int*)d_in[6];
    float* ws  = (float*)d_ws;
    float* out = (float*)d_out;

    k_init<<<(NM + 255)/256, 256, 0, stream>>>(ws);
    k_bk  <<<(BK + 255)/256, 256, 0, stream>>>(output, mask, ind, target, inde, ws);
    dim3 mg(8, NCLS, BB);
    k_main<<<mg, 256, 0, stream>>>((const float4*)pred, (const float4*)gt, ws);
    k_corr<<<(NM + 255)/256, 256, 0, stream>>>(pred, gt, ws);
    k_fin <<<1, 1, 0, stream>>>(ws, out);
}